// Round 1
// baseline (1597.065 us; speedup 1.0000x reference)
//
#include <hip/hip_runtime.h>
#include <hip/hip_bf16.h>
#include <stdint.h>

#define DD 256
#define LL 4
#define HH 8

#define BM 128
#define BN 128
#define BK 32
#define LDA 40      // LDS row stride in bf16 elems (80 B, 16B-aligned, 2-way bank alias = free)
#define CSTR 136    // epilogue LDS tile stride (ushort)

typedef __bf16 bf16_t;
typedef bf16_t bf16x8 __attribute__((ext_vector_type(8)));
typedef float f32x4 __attribute__((ext_vector_type(4)));

__device__ __forceinline__ ushort f2bf(float f) {
  union { float f; uint32_t u; } v; v.f = f;
  uint32_t r = v.u + 0x7FFFu + ((v.u >> 16) & 1u);
  return (ushort)(r >> 16);
}
__device__ __forceinline__ float bf2f(ushort u) {
  union { uint32_t u; float f; } v; v.u = ((uint32_t)u) << 16;
  return v.f;
}
// mask format: 0 = int32, 1 = uint8 (raw bool), 2 = float32
__device__ __forceinline__ bool mval(const void* m, int fmt, size_t idx) {
  if (fmt == 1) return ((const uint8_t*)m)[idx] != 0;
  if (fmt == 2) return ((const float*)m)[idx] != 0.0f;
  return ((const int*)m)[idx] != 0;
}

__global__ void detect_mask_k(const uint8_t* m, int* flag) {
  if (threadIdx.x == 0 && blockIdx.x == 0) {
    bool anybig = false, anyoff = false;
    for (int i = 0; i < 256; i++) {
      uint8_t v = m[i];
      if (v > 1) anybig = true;
      if ((i & 3) && v) anyoff = true;
    }
    *flag = anybig ? 2 : (anyoff ? 1 : 0);
  }
}

__global__ void cast_w_k(const float* __restrict__ ipw, const float* __restrict__ opw,
                         const float* __restrict__ f1w, const float* __restrict__ f2w,
                         const float* __restrict__ svw, ushort* __restrict__ W) {
  int i = blockIdx.x * 256 + threadIdx.x;
  if (i >= 458752) return;
  float v;
  if (i < 196608) v = ipw[i];
  else if (i < 262144) v = opw[i - 196608];
  else if (i < 327680) v = f1w[i - 262144];
  else if (i < 393216) v = f2w[i - 327680];
  else v = svw[i - 393216];
  W[i] = f2bf(v);
}

// EPI: 0 = plain bf16 out (+bias, opt relu), 1 = k->logits, 2 = v->ctx, 3 = save->bank slot3
template<int ABF16, int EPI>
__global__ __launch_bounds__(256, 2)
void gemm_k(const void* __restrict__ Aptr, const ushort* __restrict__ Bw,
            const float* __restrict__ bias, void* __restrict__ Cout, int M,
            const ushort* __restrict__ qbuf, const float* __restrict__ attn,
            const float* __restrict__ scores, float* __restrict__ bank_out,
            float* __restrict__ logits_out, int relu_flag, int n_tracks) {
  extern __shared__ char smem[];
  ushort* Asm = (ushort*)smem;
  ushort* Bsm = Asm + BM * LDA;
  ushort* csubh = (ushort*)smem;   // epilogue reuse (after final barrier)

  const int mt = blockIdx.x, nt = blockIdx.y;
  const int tid = threadIdx.x;
  const int wave = tid >> 6, lane = tid & 63;
  const int wm = wave >> 1, wn = wave & 1;
  const int llo = lane & 15, lhi = lane >> 4;
  const int row0 = mt * BM;

  f32x4 acc[4][4];
#pragma unroll
  for (int i = 0; i < 4; i++)
#pragma unroll
    for (int j = 0; j < 4; j++) {
      f32x4 z = {0.0f, 0.0f, 0.0f, 0.0f};
      acc[i][j] = z;
    }

  const int ar = tid >> 1;
  const int acb = (tid & 1) * 16;

  for (int k0 = 0; k0 < DD; k0 += BK) {
    // ---- stage A tile [128 x 32] (convert fp32->bf16 if needed) ----
    {
      ushort tmp[16];
      int gr = row0 + ar;
      if (ABF16) {
        if (gr < M) {
          const uint4* p = (const uint4*)((const ushort*)Aptr + (size_t)gr * DD + k0 + acb);
          *(uint4*)(tmp) = p[0];
          *(uint4*)(tmp + 8) = p[1];
        } else {
#pragma unroll
          for (int i = 0; i < 16; i++) tmp[i] = 0;
        }
      } else {
        if (gr < M) {
          const float4* p = (const float4*)((const float*)Aptr + (size_t)gr * DD + k0 + acb);
          float4 f0 = p[0], f1 = p[1], f2 = p[2], f3 = p[3];
          tmp[0] = f2bf(f0.x); tmp[1] = f2bf(f0.y); tmp[2] = f2bf(f0.z); tmp[3] = f2bf(f0.w);
          tmp[4] = f2bf(f1.x); tmp[5] = f2bf(f1.y); tmp[6] = f2bf(f1.z); tmp[7] = f2bf(f1.w);
          tmp[8] = f2bf(f2.x); tmp[9] = f2bf(f2.y); tmp[10] = f2bf(f2.z); tmp[11] = f2bf(f2.w);
          tmp[12] = f2bf(f3.x); tmp[13] = f2bf(f3.y); tmp[14] = f2bf(f3.z); tmp[15] = f2bf(f3.w);
        } else {
#pragma unroll
          for (int i = 0; i < 16; i++) tmp[i] = 0;
        }
      }
      ushort* dst = Asm + ar * LDA + acb;
      *(uint4*)dst = *(uint4*)tmp;
      *(uint4*)(dst + 8) = *(uint4*)(tmp + 8);
    }
    // ---- stage B tile [128 cols x 32 k] from bf16 weights (B^T layout = W row-major) ----
    if (tid < BN) {
      const ushort* src = Bw + (size_t)(nt * BN + tid) * DD + k0;
      ushort* dst = Bsm + tid * LDA;
      *(uint4*)(dst)      = *(const uint4*)(src);
      *(uint4*)(dst + 8)  = *(const uint4*)(src + 8);
      *(uint4*)(dst + 16) = *(const uint4*)(src + 16);
      *(uint4*)(dst + 24) = *(const uint4*)(src + 24);
    }
    __syncthreads();
    bf16x8 af[4], bfr[4];
#pragma unroll
    for (int i = 0; i < 4; i++)
      af[i] = *(const bf16x8*)(Asm + (wm * 64 + i * 16 + llo) * LDA + lhi * 8);
#pragma unroll
    for (int j = 0; j < 4; j++)
      bfr[j] = *(const bf16x8*)(Bsm + (wn * 64 + j * 16 + llo) * LDA + lhi * 8);
#pragma unroll
    for (int i = 0; i < 4; i++)
#pragma unroll
      for (int j = 0; j < 4; j++)
        acc[i][j] = __builtin_amdgcn_mfma_f32_16x16x32_bf16(af[i], bfr[j], acc[i][j], 0, 0, 0);
    __syncthreads();
  }

  // ---- epilogues ----
  if (EPI == 0) {
    ushort* C = (ushort*)Cout;
#pragma unroll
    for (int i = 0; i < 4; i++)
#pragma unroll
      for (int j = 0; j < 4; j++)
#pragma unroll
        for (int r = 0; r < 4; r++) {
          int rl = wm * 64 + i * 16 + lhi * 4 + r;
          int gr = row0 + rl;
          if (gr < M) {
            int gc = nt * BN + wn * 64 + j * 16 + llo;
            float v = acc[i][j][r] + bias[gc];
            if (relu_flag) v = fmaxf(v, 0.0f);
            C[(size_t)gr * DD + gc] = f2bf(v);
          }
        }
  } else if (EPI == 3) {
#pragma unroll
    for (int i = 0; i < 4; i++)
#pragma unroll
      for (int j = 0; j < 4; j++)
#pragma unroll
        for (int r = 0; r < 4; r++) {
          int rl = wm * 64 + i * 16 + lhi * 4 + r;
          int gr = row0 + rl;
          if (gr < M && scores[gr] > 0.0f) {
            int gc = nt * BN + wn * 64 + j * 16 + llo;
            bank_out[(size_t)gr * 1024 + 768 + gc] = acc[i][j][r] + bias[gc];
          }
        }
  } else {
    // dump tile (+bias) to LDS as bf16, then reduce
#pragma unroll
    for (int i = 0; i < 4; i++)
#pragma unroll
      for (int j = 0; j < 4; j++)
#pragma unroll
        for (int r = 0; r < 4; r++) {
          int rl = wm * 64 + i * 16 + lhi * 4 + r;
          int cl = wn * 64 + j * 16 + llo;
          int gc = nt * BN + cl;
          csubh[rl * CSTR + cl] = f2bf(acc[i][j][r] + bias[gc]);
        }
    __syncthreads();
    if (EPI == 1) {
      // logits[n, h, l] = (q[n, h-slice] . k[n, l, h-slice]) / sqrt(32)
      for (int idx = tid; idx < 512; idx += 256) {
        int trk = idx >> 4;
        int hh = (idx >> 2) & 3;
        int l = idx & 3;
        int trkg = (row0 >> 2) + trk;
        if (trkg < n_tracks) {
          const ushort* qrow = qbuf + (size_t)trkg * DD + nt * BN + hh * 32;
          float dot = 0.0f;
#pragma unroll
          for (int j2 = 0; j2 < 32; j2++)
            dot += bf2f(csubh[(trk * 4 + l) * CSTR + hh * 32 + j2]) * bf2f(qrow[j2]);
          logits_out[(size_t)trkg * 32 + (size_t)(nt * 4 + hh) * 4 + l] = dot * 0.17677669529663687f;
        }
      }
    } else {
      // ctx[n, c] = sum_l attn[n, h(c), l] * v[n, l, c]
      for (int idx = tid; idx < 32 * BN; idx += 256) {
        int trk = idx >> 7, cl = idx & 127;
        int trkg = (row0 >> 2) + trk;
        if (trkg < n_tracks) {
          int gc = nt * BN + cl;
          const float* at = attn + (size_t)trkg * 32 + (size_t)(gc >> 5) * 4;
          float v = at[0] * bf2f(csubh[(trk * 4 + 0) * CSTR + cl])
                  + at[1] * bf2f(csubh[(trk * 4 + 1) * CSTR + cl])
                  + at[2] * bf2f(csubh[(trk * 4 + 2) * CSTR + cl])
                  + at[3] * bf2f(csubh[(trk * 4 + 3) * CSTR + cl]);
          ((ushort*)Cout)[(size_t)trkg * DD + gc] = f2bf(v);
        }
      }
    }
  }
}

__global__ void softmax_k(float* __restrict__ logits, const void* __restrict__ mask,
                          const int* __restrict__ flag, int N) {
  int t = blockIdx.x * 256 + threadIdx.x;
  if (t >= N * HH) return;
  int n = t >> 3, h = t & 7;
  int fmt = *flag;
  bool valid = !mval(mask, fmt, (size_t)n * 4 + 3);
  float* p = logits + (size_t)n * 32 + h * 4;
  float lg[4];
  float mx = -3.0e38f;
#pragma unroll
  for (int l = 0; l < 4; l++) {
    lg[l] = p[l];
    if (valid && mval(mask, fmt, (size_t)n * 4 + l)) lg[l] = -1.0e9f;
    mx = fmaxf(mx, lg[l]);
  }
  float sum = 0.0f;
#pragma unroll
  for (int l = 0; l < 4; l++) { lg[l] = expf(lg[l] - mx); sum += lg[l]; }
  float inv = 1.0f / sum;
#pragma unroll
  for (int l = 0; l < 4; l++) p[l] = lg[l] * inv;
}

__global__ __launch_bounds__(256)
void ln1_k(const float* __restrict__ emb, const ushort* __restrict__ ao,
           const float* __restrict__ g, const float* __restrict__ b,
           ushort* __restrict__ eout, int N) {
  int row = blockIdx.x * 4 + (threadIdx.x >> 6);
  if (row >= N) return;
  int lane = threadIdx.x & 63;
  int c = lane * 4;
  float4 xe = *(const float4*)(emb + (size_t)row * DD + c);
  ushort4 xa = *(const ushort4*)(ao + (size_t)row * DD + c);
  float x0 = xe.x + bf2f(xa.x), x1 = xe.y + bf2f(xa.y);
  float x2 = xe.z + bf2f(xa.z), x3 = xe.w + bf2f(xa.w);
  float s = x0 + x1 + x2 + x3;
  float s2 = x0 * x0 + x1 * x1 + x2 * x2 + x3 * x3;
  for (int off = 1; off < 64; off <<= 1) {
    s += __shfl_xor(s, off);
    s2 += __shfl_xor(s2, off);
  }
  float mu = s * (1.0f / 256.0f);
  float var = s2 * (1.0f / 256.0f) - mu * mu;
  float rs = rsqrtf(var + 1e-5f);
  float4 gv = *(const float4*)(g + c);
  float4 bv = *(const float4*)(b + c);
  ushort4 r;
  r.x = f2bf((x0 - mu) * rs * gv.x + bv.x);
  r.y = f2bf((x1 - mu) * rs * gv.y + bv.y);
  r.z = f2bf((x2 - mu) * rs * gv.z + bv.z);
  r.w = f2bf((x3 - mu) * rs * gv.w + bv.w);
  *(ushort4*)(eout + (size_t)row * DD + c) = r;
}

__global__ __launch_bounds__(256)
void ln2_k(const float* __restrict__ emb, const ushort* __restrict__ e,
           const ushort* __restrict__ f, const float* __restrict__ g,
           const float* __restrict__ b, const void* __restrict__ mask,
           const int* __restrict__ flag, float* __restrict__ out_emb, int N) {
  int row = blockIdx.x * 4 + (threadIdx.x >> 6);
  if (row >= N) return;
  int lane = threadIdx.x & 63;
  int c = lane * 4;
  int fmt = *flag;
  bool valid = !mval(mask, fmt, (size_t)row * 4 + 3);
  ushort4 xe = *(const ushort4*)(e + (size_t)row * DD + c);
  ushort4 xf = *(const ushort4*)(f + (size_t)row * DD + c);
  float x0 = bf2f(xe.x) + bf2f(xf.x), x1 = bf2f(xe.y) + bf2f(xf.y);
  float x2 = bf2f(xe.z) + bf2f(xf.z), x3 = bf2f(xe.w) + bf2f(xf.w);
  float s = x0 + x1 + x2 + x3;
  float s2 = x0 * x0 + x1 * x1 + x2 * x2 + x3 * x3;
  for (int off = 1; off < 64; off <<= 1) {
    s += __shfl_xor(s, off);
    s2 += __shfl_xor(s2, off);
  }
  float mu = s * (1.0f / 256.0f);
  float var = s2 * (1.0f / 256.0f) - mu * mu;
  float rs = rsqrtf(var + 1e-5f);
  float4 gv = *(const float4*)(g + c);
  float4 bv = *(const float4*)(b + c);
  float4 o;
  if (valid) {
    o.x = (x0 - mu) * rs * gv.x + bv.x;
    o.y = (x1 - mu) * rs * gv.y + bv.y;
    o.z = (x2 - mu) * rs * gv.z + bv.z;
    o.w = (x3 - mu) * rs * gv.w + bv.w;
  } else {
    o = *(const float4*)(emb + (size_t)row * DD + c);
  }
  *(float4*)(out_emb + (size_t)row * DD + c) = o;
}

__global__ void bank_k(const float* __restrict__ memb, const float* __restrict__ scores,
                       const void* __restrict__ mask, const int* __restrict__ flag,
                       float* __restrict__ out_bank, float* __restrict__ out_mask, int N) {
  int n = blockIdx.x;
  if (n >= N) return;
  int tid = threadIdx.x;
  int l = tid >> 6, c4 = tid & 63;
  bool saved = scores[n] > 0.0f;
  const float4* mb = (const float4*)(memb + (size_t)n * 1024);
  float4* ob = (float4*)(out_bank + (size_t)n * 1024);
  if (!(saved && l == 3)) {
    int ls = saved ? l + 1 : l;
    ob[l * 64 + c4] = mb[ls * 64 + c4];
  }
  if (tid == 0) {
    int fmt = *flag;
#pragma unroll
    for (int ll2 = 0; ll2 < 4; ll2++) {
      bool mv = saved ? (ll2 < 3 ? mval(mask, fmt, (size_t)n * 4 + ll2 + 1) : false)
                      : mval(mask, fmt, (size_t)n * 4 + ll2);
      out_mask[(size_t)n * 4 + ll2] = mv ? 1.0f : 0.0f;
    }
  }
}

extern "C" void kernel_launch(void* const* d_in, const int* in_sizes, int n_in,
                              void* d_out, int out_size, void* d_ws, size_t ws_size,
                              hipStream_t stream) {
  const float* emb = (const float*)d_in[0];
  const float* scores = (const float*)d_in[1];
  const float* memb = (const float*)d_in[2];
  const void* mask = d_in[3];
  const float* svw = (const float*)d_in[4];
  const float* svb = (const float*)d_in[5];
  const float* ipw = (const float*)d_in[6];
  const float* ipb = (const float*)d_in[7];
  const float* opw = (const float*)d_in[8];
  const float* opb = (const float*)d_in[9];
  const float* f1w = (const float*)d_in[10];
  const float* f1b = (const float*)d_in[11];
  const float* f2w = (const float*)d_in[12];
  const float* f2b = (const float*)d_in[13];
  const float* g1 = (const float*)d_in[14];
  const float* b1 = (const float*)d_in[15];
  const float* g2 = (const float*)d_in[16];
  const float* b2 = (const float*)d_in[17];

  const int N = in_sizes[1];

  float* out = (float*)d_out;
  float* out_emb = out;
  float* out_bank = out + (size_t)N * DD;
  float* out_mask = out + (size_t)N * DD + (size_t)N * LL * DD;

  char* ws = (char*)d_ws;
  ushort* W = (ushort*)ws;                       // 458752 bf16 weights
  int* flag = (int*)(ws + 917504);
  float* logits = (float*)(ws + 1048576);        // [N, H, L] fp32 (attn in-place)
  size_t o = 1048576 + (size_t)N * 32 * 4;
  o = (o + 255) & ~(size_t)255;
  ushort* bufQ = (ushort*)(ws + o); o += (size_t)N * DD * 2;   // q, later h
  ushort* bufC = (ushort*)(ws + o); o += (size_t)N * DD * 2;   // ctx, later fc2-out
  ushort* bufE = (ushort*)(ws + o); o += (size_t)N * DD * 2;   // e (post-LN1)
  ushort* bufA = (ushort*)(ws + o); o += (size_t)N * DD * 2;   // attn_out

  cast_w_k<<<(458752 + 255) / 256, 256, 0, stream>>>(ipw, opw, f1w, f2w, svw, W);
  detect_mask_k<<<1, 64, 0, stream>>>((const uint8_t*)mask, flag);

  const int mtN = (N + BM - 1) / BM;
  const int mtKV = (N * LL + BM - 1) / BM;
  const dim3 blk(256);
  const size_t SM_PLAIN = (size_t)(BM + BN) * LDA * 2;         // 20480
  const size_t SM_EPI   = (size_t)128 * CSTR * 2;              // 34816

  // q = emb @ Wq^T + bq
  gemm_k<0, 0><<<dim3(mtN, 2), blk, SM_PLAIN, stream>>>(emb, W, ipb, bufQ, N,
      nullptr, nullptr, nullptr, nullptr, nullptr, 0, N);
  // k projection -> logits (scaled, unmasked)
  gemm_k<0, 1><<<dim3(mtKV, 2), blk, SM_EPI, stream>>>(memb, W + 65536, ipb + 256, nullptr, N * LL,
      bufQ, nullptr, nullptr, nullptr, logits, 0, N);
  // softmax with padding mask
  softmax_k<<<(N * HH + 255) / 256, 256, 0, stream>>>(logits, mask, flag, N);
  // v projection -> ctx
  gemm_k<0, 2><<<dim3(mtKV, 2), blk, SM_EPI, stream>>>(memb, W + 131072, ipb + 512, bufC, N * LL,
      nullptr, logits, nullptr, nullptr, nullptr, 0, N);
  // attn_out = ctx @ Wo^T + bo
  gemm_k<1, 0><<<dim3(mtN, 2), blk, SM_PLAIN, stream>>>(bufC, W + 196608, opb, bufA, N,
      nullptr, nullptr, nullptr, nullptr, nullptr, 0, N);
  // e = LN1(emb + attn_out)
  ln1_k<<<(N + 3) / 4, 256, 0, stream>>>(emb, bufA, g1, b1, bufE, N);
  // h = relu(e @ fc1^T + b1)
  gemm_k<1, 0><<<dim3(mtN, 2), blk, SM_PLAIN, stream>>>(bufE, W + 262144, f1b, bufQ, N,
      nullptr, nullptr, nullptr, nullptr, nullptr, 1, N);
  // f = h @ fc2^T + b2
  gemm_k<1, 0><<<dim3(mtN, 2), blk, SM_PLAIN, stream>>>(bufQ, W + 327680, f2b, bufC, N,
      nullptr, nullptr, nullptr, nullptr, nullptr, 0, N);
  // new_emb = valid ? LN2(e + f) : emb   (fp32 -> d_out)
  ln2_k<<<(N + 3) / 4, 256, 0, stream>>>(emb, bufE, bufC, g2, b2, mask, flag, out_emb, N);
  // save_embed -> bank slot 3 for saved rows
  gemm_k<0, 3><<<dim3(mtN, 2), blk, SM_PLAIN, stream>>>(out_emb, W + 393216, svb, nullptr, N,
      nullptr, nullptr, scores, out_bank, nullptr, 0, N);
  // bank shift/copy + new mask
  bank_k<<<N, 256, 0, stream>>>(memb, scores, mask, flag, out_bank, out_mask, N);
}